// Round 1
// baseline (200.330 us; speedup 1.0000x reference)
//
#include <hip/hip_runtime.h>
#include <math.h>

// Problem constants (match reference)
#define BB   4096
#define SS   200
#define DIN  256
#define DOUT 128

static constexpr float NORM_FACT = 0.08838834764831845f; // 1/sqrt(128)

// ---------------------------------------------------------------------------
// Kernel 0: transpose Wk [DIN][DOUT] -> WkT [DOUT][DIN] in workspace, so the
// per-block qk computation in the main kernel reads coalesced (thread i reads
// WkT[o*256 + i], consecutive threads -> consecutive addresses).
// ---------------------------------------------------------------------------
__global__ void wk_transpose_kernel(const float* __restrict__ Wk,
                                    float* __restrict__ WkT) {
    int idx = blockIdx.x * blockDim.x + threadIdx.x;  // 0 .. 32767
    if (idx < DIN * DOUT) {
        int i = idx & (DIN - 1);  // 0..255  (minor -> coalesced write)
        int o = idx >> 8;         // 0..127
        WkT[o * DIN + i] = Wk[i * DOUT + o];
    }
}

// ---------------------------------------------------------------------------
// Main fused kernel: one block per batch element b.
//   1. qk[i] = sum_o Wk[i][o] * Q[b][o]      (via WkT, coalesced)
//      qb    = sum_o Q[b][o]  * bk[o]
//   2. Stream x[b] once: score_s = x[b,s]·qk + qb; online softmax with a
//      256-dim attention-weighted-x accumulator (per wave, merged in LDS).
//   3. atten[b,s] = NORM * exp(score_s - m)/l
//      out[b]     = NORM * ((accX/l) @ Wv + bv)
// ---------------------------------------------------------------------------
__global__ __launch_bounds__(256, 4)
void attn_fused_kernel(const float* __restrict__ x,
                       const float* __restrict__ Q,
                       const float* __restrict__ WkT,
                       const float* __restrict__ bk,
                       const float* __restrict__ Wv,
                       const float* __restrict__ bv,
                       float* __restrict__ out_o,   // [BB][DOUT]
                       float* __restrict__ out_a) { // [BB][SS]
    __shared__ float Qs[DOUT];
    __shared__ float qk[DIN];
    __shared__ float scoresS[SS];
    __shared__ float accW[4][DIN];
    __shared__ float mW[4];
    __shared__ float lW[4];
    __shared__ float accF[DIN];
    __shared__ float part[2][DOUT];

    const int b    = blockIdx.x;
    const int tid  = threadIdx.x;
    const int w    = tid >> 6;   // wave id 0..3
    const int lane = tid & 63;   // lane in wave

    // ---- stage Q[b] ----
    if (tid < DOUT) Qs[tid] = Q[(size_t)b * DOUT + tid];
    __syncthreads();

    // ---- qb (redundant per thread; tiny) ----
    float qb = 0.0f;
    #pragma unroll 8
    for (int o = 0; o < DOUT; ++o) qb += Qs[o] * bk[o];

    // ---- qk[i] = sum_o WkT[o][i] * Q[b][o]  (coalesced across threads) ----
    {
        float a = 0.0f;
        #pragma unroll 4
        for (int o = 0; o < DOUT; ++o) a += WkT[o * DIN + tid] * Qs[o];
        qk[tid] = a;
    }
    __syncthreads();

    // lane j owns input dims 4j..4j+3
    const float4 qv = *reinterpret_cast<const float4*>(&qk[lane * 4]);

    // ---- streaming pass over s with online softmax ----
    float m = -INFINITY, l = 0.0f;
    float a0 = 0.0f, a1 = 0.0f, a2 = 0.0f, a3 = 0.0f;
    const float* xb = x + (size_t)b * SS * DIN;

    for (int s = w; s < SS; s += 4) {
        const float4 v = *reinterpret_cast<const float4*>(xb + s * DIN + lane * 4);
        float p = v.x * qv.x + v.y * qv.y + v.z * qv.z + v.w * qv.w;
        #pragma unroll
        for (int off = 32; off >= 1; off >>= 1) p += __shfl_xor(p, off, 64);
        const float score = p + qb;   // uniform across the wave
        if (lane == 0) scoresS[s] = score;

        if (score > m) {
            const float f = __expf(m - score);  // exp(-inf)=0 handles first iter
            a0 *= f; a1 *= f; a2 *= f; a3 *= f;
            l = l * f + 1.0f;
            m = score;
            a0 += v.x; a1 += v.y; a2 += v.z; a3 += v.w;
        } else {
            const float e = __expf(score - m);
            l += e;
            a0 += e * v.x; a1 += e * v.y; a2 += e * v.z; a3 += e * v.w;
        }
    }

    // ---- merge the 4 waves' online states ----
    accW[w][lane * 4 + 0] = a0;
    accW[w][lane * 4 + 1] = a1;
    accW[w][lane * 4 + 2] = a2;
    accW[w][lane * 4 + 3] = a3;
    if (lane == 0) { mW[w] = m; lW[w] = l; }
    __syncthreads();

    const float mf = fmaxf(fmaxf(mW[0], mW[1]), fmaxf(mW[2], mW[3]));
    const float f0 = __expf(mW[0] - mf);
    const float f1 = __expf(mW[1] - mf);
    const float f2 = __expf(mW[2] - mf);
    const float f3 = __expf(mW[3] - mf);
    const float lf = lW[0] * f0 + lW[1] * f1 + lW[2] * f2 + lW[3] * f3;

    accF[tid] = accW[0][tid] * f0 + accW[1][tid] * f1 +
                accW[2][tid] * f2 + accW[3][tid] * f3;
    __syncthreads();

    // ---- atten output: NORM * softmax ----
    if (tid < SS) {
        out_a[(size_t)b * SS + tid] = NORM_FACT * __expf(scoresS[tid] - mf) / lf;
    }

    // ---- output projection: NORM * ((accF/lf) @ Wv + bv) ----
    {
        const int o = tid & (DOUT - 1);
        const int h = tid >> 7;  // 0 or 1: split DIN range across thread halves
        float pacc = 0.0f;
        #pragma unroll 4
        for (int i = 0; i < DIN / 2; ++i) {
            const int r = h * (DIN / 2) + i;
            pacc += accF[r] * Wv[r * DOUT + o];  // coalesced in o
        }
        part[h][o] = pacc;
    }
    __syncthreads();

    if (tid < DOUT) {
        out_o[(size_t)b * DOUT + tid] =
            NORM_FACT * ((part[0][tid] + part[1][tid]) / lf + bv[tid]);
    }
}

// ---------------------------------------------------------------------------
extern "C" void kernel_launch(void* const* d_in, const int* in_sizes, int n_in,
                              void* d_out, int out_size, void* d_ws, size_t ws_size,
                              hipStream_t stream) {
    const float* x  = (const float*)d_in[0];  // [BB][SS][DIN]
    const float* Q  = (const float*)d_in[1];  // [BB][1][DOUT]
    const float* Wk = (const float*)d_in[2];  // [DIN][DOUT]
    const float* bk = (const float*)d_in[3];  // [DOUT]
    const float* Wv = (const float*)d_in[4];  // [DIN][DOUT]
    const float* bv = (const float*)d_in[5];  // [DOUT]

    float* out   = (float*)d_out;
    float* out_o = out;                       // [BB][DOUT] first in tuple order
    float* out_a = out + (size_t)BB * DOUT;   // [BB][SS]

    float* WkT = (float*)d_ws;                // 128 KiB scratch

    wk_transpose_kernel<<<(DIN * DOUT + 255) / 256, 256, 0, stream>>>(Wk, WkT);
    attn_fused_kernel<<<BB, 256, 0, stream>>>(x, Q, WkT, bk, Wv, bv, out_o, out_a);
}

// Round 2
// 181.451 us; speedup vs baseline: 1.1040x; 1.1040x over previous
//
#include <hip/hip_runtime.h>
#include <math.h>

// Problem constants (match reference)
#define BB   4096
#define SS   200
#define DIN  256
#define DOUT 128

static constexpr float NORM_FACT = 0.08838834764831845f; // 1/sqrt(128)

// ---------------------------------------------------------------------------
// Kernel 0: transpose Wk [DIN][DOUT] -> WkT [DOUT][DIN] in workspace, so the
// per-block qk computation in the main kernel reads coalesced.
// ---------------------------------------------------------------------------
__global__ void wk_transpose_kernel(const float* __restrict__ Wk,
                                    float* __restrict__ WkT) {
    int idx = blockIdx.x * blockDim.x + threadIdx.x;  // 0 .. 32767
    if (idx < DIN * DOUT) {
        int i = idx & (DIN - 1);  // 0..255  (minor -> coalesced write)
        int o = idx >> 8;         // 0..127
        WkT[o * DIN + i] = Wk[i * DOUT + o];
    }
}

// ---------------------------------------------------------------------------
// Batch-of-NB row processor: 8 independent loads in flight, 8 pipelined
// butterfly reduces, ONE online-softmax rescale per batch, then weighted
// accumulation while rows are still in registers.
// ---------------------------------------------------------------------------
template<int NB>
__device__ __forceinline__ void process_batch(const float* __restrict__ row0,
                                              const float4 qv, const float qb,
                                              float& m, float& l, float4& acc,
                                              float* __restrict__ scores_out,
                                              const int lane) {
    float4 v[NB];
    #pragma unroll
    for (int j = 0; j < NB; ++j)
        v[j] = *reinterpret_cast<const float4*>(row0 + j * DIN);

    float sc[NB];
    #pragma unroll
    for (int j = 0; j < NB; ++j) {
        float p = v[j].x * qv.x + v[j].y * qv.y + v[j].z * qv.z + v[j].w * qv.w;
        #pragma unroll
        for (int off = 32; off >= 1; off >>= 1) p += __shfl_xor(p, off, 64);
        sc[j] = p + qb;   // full sum present in ALL lanes
    }

    if (lane == 0) {
        #pragma unroll
        for (int j = 0; j < NB; ++j) scores_out[j] = sc[j];
    }

    // one rescale per batch
    float bm = sc[0];
    #pragma unroll
    for (int j = 1; j < NB; ++j) bm = fmaxf(bm, sc[j]);
    const float mn = fmaxf(m, bm);
    const float f  = __expf(m - mn);   // exp(-inf)=0 handles first batch
    acc.x *= f; acc.y *= f; acc.z *= f; acc.w *= f;
    l *= f; m = mn;

    #pragma unroll
    for (int j = 0; j < NB; ++j) {
        const float e = __expf(sc[j] - m);
        l += e;
        acc.x += e * v[j].x; acc.y += e * v[j].y;
        acc.z += e * v[j].z; acc.w += e * v[j].w;
    }
}

// ---------------------------------------------------------------------------
// Main fused kernel: one block per batch element b.
// ---------------------------------------------------------------------------
__global__ __launch_bounds__(256, 4)
void attn_fused_kernel(const float* __restrict__ x,
                       const float* __restrict__ Q,
                       const float* __restrict__ WkT,
                       const float* __restrict__ bk,
                       const float* __restrict__ Wv,
                       const float* __restrict__ bv,
                       float* __restrict__ out_o,   // [BB][DOUT]
                       float* __restrict__ out_a) { // [BB][SS]
    __shared__ float Qs[DOUT];
    __shared__ float qk[DIN];
    __shared__ float scoresS[SS];
    __shared__ float accW[4][DIN];
    __shared__ float mW[4];
    __shared__ float lW[4];
    __shared__ float accF[DIN];
    __shared__ float part[2][DOUT];

    const int b    = blockIdx.x;
    const int tid  = threadIdx.x;
    const int w    = tid >> 6;   // wave id 0..3
    const int lane = tid & 63;   // lane in wave

    // ---- stage Q[b] ----
    if (tid < DOUT) Qs[tid] = Q[(size_t)b * DOUT + tid];
    __syncthreads();

    // ---- qb (redundant per thread; tiny, bk reads become scalar loads) ----
    float qb = 0.0f;
    #pragma unroll 8
    for (int o = 0; o < DOUT; ++o) qb += Qs[o] * bk[o];

    // ---- qk[i] = sum_o WkT[o][i] * Q[b][o]  (coalesced across threads) ----
    {
        float a = 0.0f;
        #pragma unroll 8
        for (int o = 0; o < DOUT; ++o) a += WkT[o * DIN + tid] * Qs[o];
        qk[tid] = a;
    }
    __syncthreads();

    // lane j owns input dims 4j..4j+3
    const float4 qv = *reinterpret_cast<const float4*>(&qk[lane * 4]);

    // ---- streaming pass: wave w owns contiguous rows [w*50, w*50+50) ----
    float  m = -INFINITY, l = 0.0f;
    float4 acc = make_float4(0.0f, 0.0f, 0.0f, 0.0f);
    const int sBeg = w * 50;
    const float* rbase = x + (size_t)b * SS * DIN + (size_t)sBeg * DIN + lane * 4;

    #pragma unroll 1
    for (int t = 0; t < 48; t += 8)
        process_batch<8>(rbase + t * DIN, qv, qb, m, l, acc,
                         &scoresS[sBeg + t], lane);
    process_batch<2>(rbase + 48 * DIN, qv, qb, m, l, acc,
                     &scoresS[sBeg + 48], lane);

    // ---- merge the 4 waves' online states ----
    accW[w][lane * 4 + 0] = acc.x;
    accW[w][lane * 4 + 1] = acc.y;
    accW[w][lane * 4 + 2] = acc.z;
    accW[w][lane * 4 + 3] = acc.w;
    if (lane == 0) { mW[w] = m; lW[w] = l; }
    __syncthreads();

    const float mf = fmaxf(fmaxf(mW[0], mW[1]), fmaxf(mW[2], mW[3]));
    const float f0 = __expf(mW[0] - mf);
    const float f1 = __expf(mW[1] - mf);
    const float f2 = __expf(mW[2] - mf);
    const float f3 = __expf(mW[3] - mf);
    const float lf = lW[0] * f0 + lW[1] * f1 + lW[2] * f2 + lW[3] * f3;

    accF[tid] = accW[0][tid] * f0 + accW[1][tid] * f1 +
                accW[2][tid] * f2 + accW[3][tid] * f3;
    __syncthreads();

    // ---- atten output: NORM * softmax ----
    if (tid < SS) {
        out_a[(size_t)b * SS + tid] = NORM_FACT * __expf(scoresS[tid] - mf) / lf;
    }

    // ---- output projection: NORM * ((accF/lf) @ Wv + bv) ----
    {
        const int o = tid & (DOUT - 1);
        const int h = tid >> 7;  // 0 or 1: split DIN range across thread halves
        float pacc = 0.0f;
        #pragma unroll 8
        for (int i = 0; i < DIN / 2; ++i) {
            const int r = h * (DIN / 2) + i;
            pacc += accF[r] * Wv[r * DOUT + o];  // coalesced in o
        }
        part[h][o] = pacc;
    }
    __syncthreads();

    if (tid < DOUT) {
        out_o[(size_t)b * DOUT + tid] =
            NORM_FACT * ((part[0][tid] + part[1][tid]) / lf + bv[tid]);
    }
}

// ---------------------------------------------------------------------------
extern "C" void kernel_launch(void* const* d_in, const int* in_sizes, int n_in,
                              void* d_out, int out_size, void* d_ws, size_t ws_size,
                              hipStream_t stream) {
    const float* x  = (const float*)d_in[0];  // [BB][SS][DIN]
    const float* Q  = (const float*)d_in[1];  // [BB][1][DOUT]
    const float* Wk = (const float*)d_in[2];  // [DIN][DOUT]
    const float* bk = (const float*)d_in[3];  // [DOUT]
    const float* Wv = (const float*)d_in[4];  // [DIN][DOUT]
    const float* bv = (const float*)d_in[5];  // [DOUT]

    float* out   = (float*)d_out;
    float* out_o = out;                       // [BB][DOUT] first in tuple order
    float* out_a = out + (size_t)BB * DOUT;   // [BB][SS]

    float* WkT = (float*)d_ws;                // 128 KiB scratch

    wk_transpose_kernel<<<(DIN * DOUT + 255) / 256, 256, 0, stream>>>(Wk, WkT);
    attn_fused_kernel<<<BB, 256, 0, stream>>>(x, Q, WkT, bk, Wv, bv, out_o, out_a);
}